// Round 18
// baseline (537.799 us; speedup 1.0000x reference)
//
#include <hip/hip_runtime.h>
#include <math.h>

#define B_   32
#define N_   1024
#define C_   4096
#define HC_  2048
#define D_   64
#define NT_  32768           // B*N tokens
#define BKC_ 128             // K per chunk (4 sub-chunks of 32)
#define NCH_ (HC_ / BKC_)    // 16 chunks
#define TAU_ 0.01f           // exact-recompute margin on z0-z1

typedef __attribute__((ext_vector_type(8))) short s16x8;   // 8 bf16
typedef __attribute__((ext_vector_type(4))) float f32x4;

__device__ __forceinline__ float4 ld4(const float* p) {
    return *reinterpret_cast<const float4*>(p);
}
__device__ __forceinline__ unsigned short f2bf(float f) {   // RNE f32->bf16
    unsigned int u = __float_as_uint(f);
    u += 0x7fffu + ((u >> 16) & 1u);
    return (unsigned short)(u >> 16);
}
__device__ __forceinline__ float bf2f(unsigned short s) {
    return __uint_as_float(((unsigned int)s) << 16);
}

// ---------------------------------------------------------------------------
// K0: prep — split w'[k][col] = lnw[k]*w1[k][col] into bf16 hi/lo planes,
// fragment order [chunk32 64][ctile 4][lane 64][j 8].
// B-frag convention: col = ctile*16 + (lane&15), k = c32*32 + (lane>>4)*8+j.
// ---------------------------------------------------------------------------
__global__ __launch_bounds__(64) void k0_prep(
        const float* __restrict__ lnw, const float* __restrict__ w1,
        short* __restrict__ whG, short* __restrict__ wlG) {
    const int lane = threadIdx.x;
    const int c = blockIdx.x >> 2, ct = blockIdx.x & 3;
    s16x8 hv, lv;
#pragma unroll
    for (int j = 0; j < 8; ++j) {
        const int k = c * 32 + (lane >> 4) * 8 + j;
        const int col = ct * 16 + (lane & 15);
        const float v = lnw[k] * w1[(size_t)k * D_ + col];
        const unsigned short h = f2bf(v);
        hv[j] = (short)h;
        lv[j] = (short)f2bf(v - bf2f(h));
    }
    const size_t base = ((size_t)(c * 4 + ct) * 64 + lane) * 8;
    *reinterpret_cast<s16x8*>(whG + base) = hv;
    *reinterpret_cast<s16x8*>(wlG + base) = lv;
}

// ---------------------------------------------------------------------------
// MK1M v4: BARRIER-FREE MFMA GEMM (bf16x3, straight from global) +
// LN stats + upper g-accum.  grid 512 (M64 tiles), block 256 (wave = ctile).
// Phase G: lane's A-frag for (rg,kk) = 32 contiguous bytes of row
//   T0+rg*16+(lane&15); wave covers 16 rows x 128B contiguous (perfectly
//   coalesced); 4 waves read identical x addresses -> L1 reuse; B-frags
//   per-wave from L2.  No LDS, no barriers, no staging: loads -> convert ->
//   MFMA, compiler-scheduled.  Stats: wave w owns rg==w rows.
// Phase U: unchanged (r12-verbatim).
// ---------------------------------------------------------------------------
__global__ __launch_bounds__(256) void mk1m(
        const float* __restrict__ x, const float* __restrict__ lnw,
        const float* __restrict__ lnb, const short* __restrict__ whG,
        const short* __restrict__ wlG, float* __restrict__ Pp,
        float* __restrict__ muv, float* __restrict__ rsv,
        float* __restrict__ part) {
    __shared__ float sh[4][HC_];       // 32 KB (phase-U reduce only)
    __shared__ float sLow[64], qLow[64];

    const int t = threadIdx.x;
    const int tid = blockIdx.x;
    const int T0 = tid * 64;
    const int lane = t & 63, w = t >> 6;         // wave = ctile
    const int l15 = lane & 15, kg = lane >> 4;   // row-in-group / k-group

    // ===================== Phase G: barrier-free MFMA GEMM =================
    f32x4 acc[4];
#pragma unroll
    for (int rg = 0; rg < 4; ++rg)
#pragma unroll
        for (int r = 0; r < 4; ++r) acc[rg][r] = 0.f;
    float sA = 0.f, qA = 0.f;          // stats for rg == w rows only

    const s16x8* wp = reinterpret_cast<const s16x8*>(whG);
    const s16x8* lp = reinterpret_cast<const s16x8*>(wlG);

#pragma unroll 1
    for (int c = 0; c < NCH_; ++c) {
#pragma unroll
        for (int kk = 0; kk < 4; ++kk) {
            const s16x8 bh = wp[((size_t)(c * 4 + kk) * 4 + w) * 64 + lane];
            const s16x8 bl = lp[((size_t)(c * 4 + kk) * 4 + w) * 64 + lane];
            const int k0 = c * BKC_ + kk * 32 + kg * 8;
#pragma unroll
            for (int rg = 0; rg < 4; ++rg) {
                const int row = T0 + rg * 16 + l15;
                const float* rp = x + (size_t)row * C_ + k0;
                const float4 xa = ld4(rp);
                const float4 xb = ld4(rp + 4);
                const float xs[8] = {xa.x, xa.y, xa.z, xa.w,
                                     xb.x, xb.y, xb.z, xb.w};
                s16x8 Ah, Al;
#pragma unroll
                for (int j = 0; j < 8; ++j) {
                    const unsigned short h = f2bf(xs[j]);
                    Ah[j] = (short)h;
                    Al[j] = (short)f2bf(xs[j] - bf2f(h));
                }
                if (rg == w) {         // wave-uniform: this wave's rows
                    sA += ((xs[0] + xs[1]) + (xs[2] + xs[3]))
                        + ((xs[4] + xs[5]) + (xs[6] + xs[7]));
#pragma unroll
                    for (int j = 0; j < 8; ++j)
                        qA = fmaf(xs[j], xs[j], qA);
                }
                acc[rg] = __builtin_amdgcn_mfma_f32_16x16x32_bf16(
                    Ah, bh, acc[rg], 0, 0, 0);
                acc[rg] = __builtin_amdgcn_mfma_f32_16x16x32_bf16(
                    Al, bh, acc[rg], 0, 0, 0);
                acc[rg] = __builtin_amdgcn_mfma_f32_16x16x32_bf16(
                    Ah, bl, acc[rg], 0, 0, 0);
            }
        }
    }
    // ---- stats reduce over k-groups (lanes differing in bits 4-5) ----
    sA += __shfl_xor(sA, 16); qA += __shfl_xor(qA, 16);
    sA += __shfl_xor(sA, 32); qA += __shfl_xor(qA, 32);
    if (lane < 16) {
        sLow[w * 16 + lane] = sA;
        qLow[w * 16 + lane] = qA;
    }
    // ---- write P: D layout col=lane&15, row=(lane>>4)*4+reg (m89) ----
#pragma unroll
    for (int rg = 0; rg < 4; ++rg)
#pragma unroll
        for (int r = 0; r < 4; ++r) {
            const int tok = T0 + rg * 16 + kg * 4 + r;
            Pp[(size_t)tok * D_ + w * 16 + l15] = acc[rg][r];
        }
    __syncthreads();   // sLow/qLow ready

    // ===================== Phase U: upper stats + g-accum ==================
    float4 wv[8], bv[8], gacc[8];
#pragma unroll
    for (int m = 0; m < 8; ++m) {
        wv[m] = ld4(lnw + HC_ + (m * 64 + lane) * 4);
        bv[m] = ld4(lnb + HC_ + (m * 64 + lane) * 4);
        gacc[m] = make_float4(0.f, 0.f, 0.f, 0.f);
    }
    for (int i = 0; i < 16; ++i) {
        const int r = w * 16 + i;
        const int tok = T0 + r;
        const float* rowp = x + (size_t)tok * C_ + HC_;
        float4 v[8];
        float s = 0.f, q = 0.f;
#pragma unroll
        for (int m = 0; m < 8; ++m) {
            v[m] = ld4(rowp + (m * 64 + lane) * 4);
            s += (v[m].x + v[m].y) + (v[m].z + v[m].w);
            q = fmaf(v[m].x, v[m].x, fmaf(v[m].y, v[m].y,
                fmaf(v[m].z, v[m].z, fmaf(v[m].w, v[m].w, q))));
        }
#pragma unroll
        for (int o = 1; o < 64; o <<= 1) {
            s += __shfl_xor(s, o);
            q += __shfl_xor(q, o);
        }
        const float S_ = s + sLow[r];
        const float Q_ = q + qLow[r];
        const float mu = S_ * (1.f / C_);
        const float rs = rsqrtf(Q_ * (1.f / C_) - mu * mu + 1e-5f);
        if (lane == 0) {
            muv[tok] = mu;
            rsv[tok] = rs;
        }
#pragma unroll
        for (int m = 0; m < 8; ++m) {
            gacc[m].x += (v[m].x - mu) * rs * wv[m].x + bv[m].x;
            gacc[m].y += (v[m].y - mu) * rs * wv[m].y + bv[m].y;
            gacc[m].z += (v[m].z - mu) * rs * wv[m].z + bv[m].z;
            gacc[m].w += (v[m].w - mu) * rs * wv[m].w + bv[m].w;
        }
    }
    __syncthreads();   // sLow reads done; sh[] free
#pragma unroll
    for (int m = 0; m < 8; ++m)
        *reinterpret_cast<float4*>(&sh[w][(m * 64 + lane) * 4]) = gacc[m];
    __syncthreads();
    float* pp = part + (size_t)tid * HC_;
#pragma unroll
    for (int m = 0; m < 8; ++m) {
        const int j = (m * 64 + lane) * 4;
        const float4 a0 = ld4(&sh[0][j]);
        const float4 a1 = ld4(&sh[1][j]);
        const float4 a2 = ld4(&sh[2][j]);
        const float4 a3 = ld4(&sh[3][j]);
        float4 r;
        r.x = (a0.x + a1.x) + (a2.x + a3.x);
        r.y = (a0.y + a1.y) + (a2.y + a3.y);
        r.z = (a0.z + a1.z) + (a2.z + a3.z);
        r.w = (a0.w + a1.w) + (a2.w + a3.w);
        if (w == (m & 3))
            *reinterpret_cast<float4*>(pp + j) = r;
    }
}

// ---------------------------------------------------------------------------
// K2a: fold partial-reduce + partial GEMVs.  grid 264, block 256.
// ---------------------------------------------------------------------------
__global__ __launch_bounds__(256) void k2a_part(
        const float* __restrict__ part, const float* __restrict__ w1,
        const float* __restrict__ lnw, const float* __restrict__ lnb,
        float* __restrict__ gpart, float* __restrict__ Wpart,
        float* __restrict__ Bpart) {
    __shared__ float Gs[256];
    __shared__ float red[512];
    const int t = threadIdx.x;
    const int d = t & 63, s = t >> 6;
    const int blk = blockIdx.x;
    if (blk < 256) {
        const int b = blk >> 3, jq = blk & 7;
        const int j = jq * 256 + t;
        float a = 0.f;
        for (int k = 0; k < 16; ++k)
            a += part[(size_t)(b * 16 + k) * HC_ + j];
        Gs[t] = a;
        __syncthreads();
        float acc = 0.f;
        const int j0 = jq * 256 + s * 64;
        for (int jj = 0; jj < 64; ++jj)
            acc = fmaf(Gs[s * 64 + jj],
                       w1[(size_t)(HC_ + j0 + jj) * D_ + d], acc);
        red[s * 64 + d] = acc;
        __syncthreads();
        if (s == 0)
            gpart[(size_t)blk * 64 + d] =
                red[d] + red[64 + d] + red[128 + d] + red[192 + d];
    } else {
        const int wq = blk - 256;
        const int c0 = wq * 256 + s * 64;
        float a = 0.f, c2 = 0.f;
        for (int c = c0; c < c0 + 64; ++c) {
            const float wvv = w1[(size_t)c * D_ + d];
            a = fmaf(lnw[c], wvv, a);
            c2 = fmaf(lnb[c], wvv, c2);
        }
        red[s * 64 + d] = a;
        red[256 + s * 64 + d] = c2;
        __syncthreads();
        if (s == 0) {
            Wpart[wq * 64 + d] =
                red[d] + red[64 + d] + red[128 + d] + red[192 + d];
            Bpart[wq * 64 + d] = red[256 + d] + red[320 + d]
                               + red[384 + d] + red[448 + d];
        }
    }
}

// ---------------------------------------------------------------------------
// K45: decision (k2b folded) + masked copy + dz store.  One wave per token.
// ---------------------------------------------------------------------------
__global__ __launch_bounds__(256) void k45_decide_mask(
        const float* __restrict__ Pp, const float* __restrict__ muv,
        const float* __restrict__ rsv, const float* __restrict__ gpart,
        const float* __restrict__ Wpart, const float* __restrict__ Bpart,
        const float* __restrict__ b1, const float* __restrict__ w2,
        const float* __restrict__ b2, const float* __restrict__ gum,
        const float* __restrict__ x, float* __restrict__ out,
        float* __restrict__ dzv) {
    const int t = threadIdx.x;
    const int lane = t & 63, w = t >> 6;
    const int token = blockIdx.x * 4 + w;
    const int b = token >> 10;

    float W1 = 0.f, Bsv = 0.f, gt = 0.f;
#pragma unroll
    for (int q = 0; q < 8; ++q) {
        W1 += Wpart[q * 64 + lane];
        Bsv += Bpart[q * 64 + lane];
        gt += gpart[(size_t)(b * 8 + q) * 64 + lane];
    }
    gt *= (1.f / N_);

    const float2 gv = *reinterpret_cast<const float2*>(gum + token * 2);
    const float p = Pp[(size_t)token * D_ + lane];
    const float mu = muv[token], rs = rsv[token];
    float h = rs * (p - mu * W1) + Bsv + gt + b1[lane];
    h = 0.5f * h * (1.f + erff(h * 0.70710678118654752f));   // exact gelu
    const float2 w2v = *reinterpret_cast<const float2*>(w2 + lane * 2);
    float l0 = h * w2v.x;
    float l1 = h * w2v.y;
#pragma unroll
    for (int o = 1; o < 64; o <<= 1) {
        l0 += __shfl_xor(l0, o);
        l1 += __shfl_xor(l1, o);
    }
    const float z0 = l0 + b2[0] + gv.x;
    const float z1 = l1 + b2[1] + gv.y;
    if (lane == 0) dzv[token] = z0 - z1;

    float4* dst = reinterpret_cast<float4*>(out + (size_t)token * C_);
    if (z0 >= z1) {    // keep (argmax ties -> index 0): copy x
        const float4* src =
            reinterpret_cast<const float4*>(x + (size_t)token * C_);
#pragma unroll
        for (int c = 0; c < 16; ++c)
            dst[c * 64 + lane] = src[c * 64 + lane];
    } else {           // drop: write zeros, skip the x read
        const float4 z = make_float4(0.f, 0.f, 0.f, 0.f);
#pragma unroll
        for (int c = 0; c < 16; ++c)
            dst[c * 64 + lane] = z;
    }
}

// ---------------------------------------------------------------------------
// K6: cleanup — exact f32 recompute for |dz| < TAU_, unrolled x16 (MLP~24).
// ---------------------------------------------------------------------------
__global__ __launch_bounds__(256) void k6_cleanup(
        const float* __restrict__ x, const float* __restrict__ lnw,
        const float* __restrict__ w1, const float* __restrict__ muv,
        const float* __restrict__ rsv, const float* __restrict__ gpart,
        const float* __restrict__ Wpart, const float* __restrict__ Bpart,
        const float* __restrict__ b1, const float* __restrict__ w2,
        const float* __restrict__ b2, const float* __restrict__ gum,
        const float* __restrict__ dzv, float* __restrict__ out) {
    const int t = threadIdx.x;
    const int lane = t & 63, w = t >> 6;
    const int token = blockIdx.x * 4 + w;
    const float dz = dzv[token];
    if (fabsf(dz) >= TAU_) return;    // wave-uniform

    const float* xr = x + (size_t)token * C_;
    float pa[4] = {0.f, 0.f, 0.f, 0.f};
#pragma unroll 1
    for (int k = 0; k < HC_; k += 16) {
        const float4 xk0 = ld4(xr + k), xk1 = ld4(xr + k + 4);
        const float4 xk2 = ld4(xr + k + 8), xk3 = ld4(xr + k + 12);
        const float4 wk0 = ld4(lnw + k), wk1 = ld4(lnw + k + 4);
        const float4 wk2 = ld4(lnw + k + 8), wk3 = ld4(lnw + k + 12);
        float w1v[16];
#pragma unroll
        for (int j = 0; j < 16; ++j)
            w1v[j] = w1[(size_t)(k + j) * D_ + lane];
        const float xs[16] = {xk0.x * wk0.x, xk0.y * wk0.y,
                              xk0.z * wk0.z, xk0.w * wk0.w,
                              xk1.x * wk1.x, xk1.y * wk1.y,
                              xk1.z * wk1.z, xk1.w * wk1.w,
                              xk2.x * wk2.x, xk2.y * wk2.y,
                              xk2.z * wk2.z, xk2.w * wk2.w,
                              xk3.x * wk3.x, xk3.y * wk3.y,
                              xk3.z * wk3.z, xk3.w * wk3.w};
#pragma unroll
        for (int j = 0; j < 16; ++j)
            pa[j & 3] = fmaf(xs[j], w1v[j], pa[j & 3]);
    }
    const float p = (pa[0] + pa[1]) + (pa[2] + pa[3]);

    const int b = token >> 10;
    float W1 = 0.f, Bsv = 0.f, gt = 0.f;
#pragma unroll
    for (int q = 0; q < 8; ++q) {
        W1 += Wpart[q * 64 + lane];
        Bsv += Bpart[q * 64 + lane];
        gt += gpart[(size_t)(b * 8 + q) * 64 + lane];
    }
    gt *= (1.f / N_);
    const float2 gv = *reinterpret_cast<const float2*>(gum + token * 2);
    const float mu = muv[token], rs = rsv[token];
    float h = rs * (p - mu * W1) + Bsv + gt + b1[lane];
    h = 0.5f * h * (1.f + erff(h * 0.70710678118654752f));
    const float2 w2v = *reinterpret_cast<const float2*>(w2 + lane * 2);
    float l0 = h * w2v.x;
    float l1 = h * w2v.y;
#pragma unroll
    for (int o = 1; o < 64; o <<= 1) {
        l0 += __shfl_xor(l0, o);
        l1 += __shfl_xor(l1, o);
    }
    const float z0 = l0 + b2[0] + gv.x;
    const float z1 = l1 + b2[1] + gv.y;
    const bool keepNew = (z0 >= z1);
    const bool keepOld = (dz >= 0.f);
    if (keepNew == keepOld) return;

    float4* dst = reinterpret_cast<float4*>(out + (size_t)token * C_);
    if (keepNew) {
        const float4* src = reinterpret_cast<const float4*>(xr);
#pragma unroll
        for (int c = 0; c < 16; ++c)
            dst[c * 64 + lane] = src[c * 64 + lane];
    } else {
        const float4 z = make_float4(0.f, 0.f, 0.f, 0.f);
#pragma unroll
        for (int c = 0; c < 16; ++c)
            dst[c * 64 + lane] = z;
    }
}

// ---------------------------------------------------------------------------
extern "C" void kernel_launch(void* const* d_in, const int* in_sizes, int n_in,
                              void* d_out, int out_size, void* d_ws,
                              size_t ws_size, hipStream_t stream) {
    const float* x   = (const float*)d_in[0];
    const float* gum = (const float*)d_in[1];
    const float* lnw = (const float*)d_in[2];
    const float* lnb = (const float*)d_in[3];
    const float* w1  = (const float*)d_in[4];
    const float* b1  = (const float*)d_in[5];
    const float* w2  = (const float*)d_in[6];
    const float* b2  = (const float*)d_in[7];
    float* out = (float*)d_out;

    float* wsf   = (float*)d_ws;
    float* Pp    = wsf;                                   // 32768*64
    float* muv   = Pp + (size_t)NT_ * D_;                 // 32768
    float* rsv   = muv + NT_;                             // 32768
    float* part  = rsv + NT_;                             // 512*2048
    float* gpart = part + (size_t)512 * HC_;              // 256*64
    float* Wpart = gpart + 256 * 64;                      // 8*64
    float* Bpart = Wpart + 8 * 64;                        // 8*64
    float* dzv   = Bpart + 8 * 64;                        // 32768
    short* whG   = (short*)(dzv + NT_);                   // 131072 shorts
    short* wlG   = whG + (size_t)131072;                  // 131072 shorts

    k0_prep<<<256, 64, 0, stream>>>(lnw, w1, whG, wlG);
    mk1m<<<512, 256, 0, stream>>>(x, lnw, lnb, whG, wlG, Pp, muv, rsv, part);
    k2a_part<<<264, 256, 0, stream>>>(part, w1, lnw, lnb,
                                      gpart, Wpart, Bpart);
    k45_decide_mask<<<NT_ / 4, 256, 0, stream>>>(Pp, muv, rsv, gpart,
                                                 Wpart, Bpart, b1, w2, b2,
                                                 gum, x, out, dzv);
    k6_cleanup<<<NT_ / 4, 256, 0, stream>>>(x, lnw, w1, muv, rsv, gpart,
                                            Wpart, Bpart, b1, w2, b2,
                                            gum, dzv, out);
}

// Round 19
// 445.742 us; speedup vs baseline: 1.2065x; 1.2065x over previous
//
#include <hip/hip_runtime.h>
#include <math.h>

#define B_   32
#define N_   1024
#define C_   4096
#define HC_  2048
#define D_   64
#define NT_  32768           // B*N tokens
#define BKC_ 128             // K per chunk (4 sub-chunks of 32)
#define NCH_ (HC_ / BKC_)    // 16 chunks
#define TAU_ 0.01f           // exact-recompute margin on z0-z1

typedef __attribute__((ext_vector_type(8))) short s16x8;   // 8 bf16
typedef __attribute__((ext_vector_type(4))) float f32x4;

__device__ __forceinline__ float4 ld4(const float* p) {
    return *reinterpret_cast<const float4*>(p);
}
__device__ __forceinline__ unsigned short f2bf(float f) {   // RNE f32->bf16
    unsigned int u = __float_as_uint(f);
    u += 0x7fffu + ((u >> 16) & 1u);
    return (unsigned short)(u >> 16);
}

// ---------------------------------------------------------------------------
// K0: prep — wh[k][col] = bf16(lnw[k]*w1[k][col]), fragment order
// [chunk32 64][ctile 4][lane 64][j 8].
// B-frag convention: col = ctile*16 + (lane&15), k = c32*32 + (lane>>4)*8+j.
// ---------------------------------------------------------------------------
__global__ __launch_bounds__(64) void k0_prep(
        const float* __restrict__ lnw, const float* __restrict__ w1,
        short* __restrict__ whG) {
    const int lane = threadIdx.x;
    const int c = blockIdx.x >> 2, ct = blockIdx.x & 3;
    s16x8 hv;
#pragma unroll
    for (int j = 0; j < 8; ++j) {
        const int k = c * 32 + (lane >> 4) * 8 + j;
        const int col = ct * 16 + (lane & 15);
        hv[j] = (short)f2bf(lnw[k] * w1[(size_t)k * D_ + col]);
    }
    *reinterpret_cast<s16x8*>(
        whG + ((size_t)(c * 4 + ct) * 64 + lane) * 8) = hv;
}

// ---------------------------------------------------------------------------
// MK1M v5: pure-bf16 MFMA GEMM, register-double-buffered batched loads
// (8 independent b128 per step in flight), barrier-free phase G.
// grid 512 (M64 tiles), block 256 (wave = ctile).
// Numerics: bf16 product error (~2e-4 on dz) is covered by k6's exact-f32
// recompute for |dz| < TAU_ = 0.01 (~50 sigma margin).
// Phase U: unchanged.
// ---------------------------------------------------------------------------
__global__ __launch_bounds__(256) void mk1m(
        const float* __restrict__ x, const float* __restrict__ lnw,
        const float* __restrict__ lnb, const short* __restrict__ whG,
        float* __restrict__ Pp, float* __restrict__ muv,
        float* __restrict__ rsv, float* __restrict__ part) {
    __shared__ float sh[4][HC_];       // 32 KB (phase-U reduce only)
    __shared__ float sLow[64], qLow[64];

    const int t = threadIdx.x;
    const int tid = blockIdx.x;
    const int T0 = tid * 64;
    const int lane = t & 63, w = t >> 6;         // wave = ctile
    const int l15 = lane & 15, kg = lane >> 4;   // row-in-group / k-group

    // ===================== Phase G: streamed MFMA GEMM =====================
    f32x4 acc[4];
#pragma unroll
    for (int rg = 0; rg < 4; ++rg)
#pragma unroll
        for (int r = 0; r < 4; ++r) acc[rg][r] = 0.f;
    float sA = 0.f, qA = 0.f;          // stats for rg == w rows only

    const s16x8* wp = reinterpret_cast<const s16x8*>(whG);
    float4 xn[8];                      // next-step x (4 kk x 32B)
    s16x8 bhC[4], bhN[4];
    {   // prologue: step (c=0, rg=0) x + chunk-0 B
        const float* rp = x + (size_t)(T0 + l15) * C_ + kg * 8;
#pragma unroll
        for (int kk = 0; kk < 4; ++kk) {
            xn[kk * 2] = ld4(rp + kk * 32);
            xn[kk * 2 + 1] = ld4(rp + kk * 32 + 4);
        }
#pragma unroll
        for (int kk = 0; kk < 4; ++kk)
            bhC[kk] = wp[(size_t)(kk * 4 + w) * 64 + lane];
    }

#pragma unroll 1
    for (int c = 0; c < NCH_; ++c) {
        // prefetch next chunk's B frags (L2-resident)
        if (c + 1 < NCH_) {
#pragma unroll
            for (int kk = 0; kk < 4; ++kk)
                bhN[kk] = wp[((size_t)(c + 1) * 4 + kk) * 4 * 64
                             + (size_t)w * 64 + lane];
        }
#pragma unroll
        for (int rg = 0; rg < 4; ++rg) {
            float4 xv[8];
#pragma unroll
            for (int i = 0; i < 8; ++i) xv[i] = xn[i];
            // issue next step's 8 independent loads (covers latency)
            const int ns = c * 4 + rg + 1;
            if (ns < NCH_ * 4) {
                const int nc = ns >> 2, nrg = ns & 3;
                const float* rp = x + (size_t)(T0 + nrg * 16 + l15) * C_
                                  + nc * BKC_ + kg * 8;
#pragma unroll
                for (int kk = 0; kk < 4; ++kk) {
                    xn[kk * 2] = ld4(rp + kk * 32);
                    xn[kk * 2 + 1] = ld4(rp + kk * 32 + 4);
                }
            }
            // convert + stats + 4 MFMA
            if (rg == w) {             // wave-uniform
#pragma unroll
                for (int i = 0; i < 8; ++i) {
                    sA += ((xv[i].x + xv[i].y) + (xv[i].z + xv[i].w));
                    qA = fmaf(xv[i].x, xv[i].x, fmaf(xv[i].y, xv[i].y,
                         fmaf(xv[i].z, xv[i].z,
                         fmaf(xv[i].w, xv[i].w, qA))));
                }
            }
#pragma unroll
            for (int kk = 0; kk < 4; ++kk) {
                const float xs[8] = {
                    xv[kk * 2].x, xv[kk * 2].y, xv[kk * 2].z, xv[kk * 2].w,
                    xv[kk * 2 + 1].x, xv[kk * 2 + 1].y,
                    xv[kk * 2 + 1].z, xv[kk * 2 + 1].w};
                s16x8 Ah;
#pragma unroll
                for (int j = 0; j < 8; ++j) Ah[j] = (short)f2bf(xs[j]);
                acc[rg] = __builtin_amdgcn_mfma_f32_16x16x32_bf16(
                    Ah, bhC[kk], acc[rg], 0, 0, 0);
            }
        }
#pragma unroll
        for (int kk = 0; kk < 4; ++kk) bhC[kk] = bhN[kk];
    }
    // ---- stats reduce over k-groups ----
    sA += __shfl_xor(sA, 16); qA += __shfl_xor(qA, 16);
    sA += __shfl_xor(sA, 32); qA += __shfl_xor(qA, 32);
    if (lane < 16) {
        sLow[w * 16 + lane] = sA;
        qLow[w * 16 + lane] = qA;
    }
    // ---- write P: D layout col=lane&15, row=(lane>>4)*4+reg (m89) ----
#pragma unroll
    for (int rg = 0; rg < 4; ++rg)
#pragma unroll
        for (int r = 0; r < 4; ++r) {
            const int tok = T0 + rg * 16 + kg * 4 + r;
            Pp[(size_t)tok * D_ + w * 16 + l15] = acc[rg][r];
        }
    __syncthreads();   // sLow/qLow ready

    // ===================== Phase U: upper stats + g-accum ==================
    float4 wv[8], bv[8], gacc[8];
#pragma unroll
    for (int m = 0; m < 8; ++m) {
        wv[m] = ld4(lnw + HC_ + (m * 64 + lane) * 4);
        bv[m] = ld4(lnb + HC_ + (m * 64 + lane) * 4);
        gacc[m] = make_float4(0.f, 0.f, 0.f, 0.f);
    }
    for (int i = 0; i < 16; ++i) {
        const int r = w * 16 + i;
        const int tok = T0 + r;
        const float* rowp = x + (size_t)tok * C_ + HC_;
        float4 v[8];
        float s = 0.f, q = 0.f;
#pragma unroll
        for (int m = 0; m < 8; ++m) {
            v[m] = ld4(rowp + (m * 64 + lane) * 4);
            s += (v[m].x + v[m].y) + (v[m].z + v[m].w);
            q = fmaf(v[m].x, v[m].x, fmaf(v[m].y, v[m].y,
                fmaf(v[m].z, v[m].z, fmaf(v[m].w, v[m].w, q))));
        }
#pragma unroll
        for (int o = 1; o < 64; o <<= 1) {
            s += __shfl_xor(s, o);
            q += __shfl_xor(q, o);
        }
        const float S_ = s + sLow[r];
        const float Q_ = q + qLow[r];
        const float mu = S_ * (1.f / C_);
        const float rs = rsqrtf(Q_ * (1.f / C_) - mu * mu + 1e-5f);
        if (lane == 0) {
            muv[tok] = mu;
            rsv[tok] = rs;
        }
#pragma unroll
        for (int m = 0; m < 8; ++m) {
            gacc[m].x += (v[m].x - mu) * rs * wv[m].x + bv[m].x;
            gacc[m].y += (v[m].y - mu) * rs * wv[m].y + bv[m].y;
            gacc[m].z += (v[m].z - mu) * rs * wv[m].z + bv[m].z;
            gacc[m].w += (v[m].w - mu) * rs * wv[m].w + bv[m].w;
        }
    }
    __syncthreads();   // sLow reads done; sh[] free
#pragma unroll
    for (int m = 0; m < 8; ++m)
        *reinterpret_cast<float4*>(&sh[w][(m * 64 + lane) * 4]) = gacc[m];
    __syncthreads();
    float* pp = part + (size_t)tid * HC_;
#pragma unroll
    for (int m = 0; m < 8; ++m) {
        const int j = (m * 64 + lane) * 4;
        const float4 a0 = ld4(&sh[0][j]);
        const float4 a1 = ld4(&sh[1][j]);
        const float4 a2 = ld4(&sh[2][j]);
        const float4 a3 = ld4(&sh[3][j]);
        float4 r;
        r.x = (a0.x + a1.x) + (a2.x + a3.x);
        r.y = (a0.y + a1.y) + (a2.y + a3.y);
        r.z = (a0.z + a1.z) + (a2.z + a3.z);
        r.w = (a0.w + a1.w) + (a2.w + a3.w);
        if (w == (m & 3))
            *reinterpret_cast<float4*>(pp + j) = r;
    }
}

// ---------------------------------------------------------------------------
// K2a: fold partial-reduce + partial GEMVs.  grid 264, block 256.
// ---------------------------------------------------------------------------
__global__ __launch_bounds__(256) void k2a_part(
        const float* __restrict__ part, const float* __restrict__ w1,
        const float* __restrict__ lnw, const float* __restrict__ lnb,
        float* __restrict__ gpart, float* __restrict__ Wpart,
        float* __restrict__ Bpart) {
    __shared__ float Gs[256];
    __shared__ float red[512];
    const int t = threadIdx.x;
    const int d = t & 63, s = t >> 6;
    const int blk = blockIdx.x;
    if (blk < 256) {
        const int b = blk >> 3, jq = blk & 7;
        const int j = jq * 256 + t;
        float a = 0.f;
        for (int k = 0; k < 16; ++k)
            a += part[(size_t)(b * 16 + k) * HC_ + j];
        Gs[t] = a;
        __syncthreads();
        float acc = 0.f;
        const int j0 = jq * 256 + s * 64;
        for (int jj = 0; jj < 64; ++jj)
            acc = fmaf(Gs[s * 64 + jj],
                       w1[(size_t)(HC_ + j0 + jj) * D_ + d], acc);
        red[s * 64 + d] = acc;
        __syncthreads();
        if (s == 0)
            gpart[(size_t)blk * 64 + d] =
                red[d] + red[64 + d] + red[128 + d] + red[192 + d];
    } else {
        const int wq = blk - 256;
        const int c0 = wq * 256 + s * 64;
        float a = 0.f, c2 = 0.f;
        for (int c = c0; c < c0 + 64; ++c) {
            const float wvv = w1[(size_t)c * D_ + d];
            a = fmaf(lnw[c], wvv, a);
            c2 = fmaf(lnb[c], wvv, c2);
        }
        red[s * 64 + d] = a;
        red[256 + s * 64 + d] = c2;
        __syncthreads();
        if (s == 0) {
            Wpart[wq * 64 + d] =
                red[d] + red[64 + d] + red[128 + d] + red[192 + d];
            Bpart[wq * 64 + d] = red[256 + d] + red[320 + d]
                               + red[384 + d] + red[448 + d];
        }
    }
}

// ---------------------------------------------------------------------------
// K45: decision (k2b folded) + masked copy + dz store.  One wave per token.
// ---------------------------------------------------------------------------
__global__ __launch_bounds__(256) void k45_decide_mask(
        const float* __restrict__ Pp, const float* __restrict__ muv,
        const float* __restrict__ rsv, const float* __restrict__ gpart,
        const float* __restrict__ Wpart, const float* __restrict__ Bpart,
        const float* __restrict__ b1, const float* __restrict__ w2,
        const float* __restrict__ b2, const float* __restrict__ gum,
        const float* __restrict__ x, float* __restrict__ out,
        float* __restrict__ dzv) {
    const int t = threadIdx.x;
    const int lane = t & 63, w = t >> 6;
    const int token = blockIdx.x * 4 + w;
    const int b = token >> 10;

    float W1 = 0.f, Bsv = 0.f, gt = 0.f;
#pragma unroll
    for (int q = 0; q < 8; ++q) {
        W1 += Wpart[q * 64 + lane];
        Bsv += Bpart[q * 64 + lane];
        gt += gpart[(size_t)(b * 8 + q) * 64 + lane];
    }
    gt *= (1.f / N_);

    const float2 gv = *reinterpret_cast<const float2*>(gum + token * 2);
    const float p = Pp[(size_t)token * D_ + lane];
    const float mu = muv[token], rs = rsv[token];
    float h = rs * (p - mu * W1) + Bsv + gt + b1[lane];
    h = 0.5f * h * (1.f + erff(h * 0.70710678118654752f));   // exact gelu
    const float2 w2v = *reinterpret_cast<const float2*>(w2 + lane * 2);
    float l0 = h * w2v.x;
    float l1 = h * w2v.y;
#pragma unroll
    for (int o = 1; o < 64; o <<= 1) {
        l0 += __shfl_xor(l0, o);
        l1 += __shfl_xor(l1, o);
    }
    const float z0 = l0 + b2[0] + gv.x;
    const float z1 = l1 + b2[1] + gv.y;
    if (lane == 0) dzv[token] = z0 - z1;

    float4* dst = reinterpret_cast<float4*>(out + (size_t)token * C_);
    if (z0 >= z1) {    // keep (argmax ties -> index 0): copy x
        const float4* src =
            reinterpret_cast<const float4*>(x + (size_t)token * C_);
#pragma unroll
        for (int c = 0; c < 16; ++c)
            dst[c * 64 + lane] = src[c * 64 + lane];
    } else {           // drop: write zeros, skip the x read
        const float4 z = make_float4(0.f, 0.f, 0.f, 0.f);
#pragma unroll
        for (int c = 0; c < 16; ++c)
            dst[c * 64 + lane] = z;
    }
}

// ---------------------------------------------------------------------------
// K6: cleanup — exact f32 recompute for |dz| < TAU_, unrolled x16 (MLP~24).
// ---------------------------------------------------------------------------
__global__ __launch_bounds__(256) void k6_cleanup(
        const float* __restrict__ x, const float* __restrict__ lnw,
        const float* __restrict__ w1, const float* __restrict__ muv,
        const float* __restrict__ rsv, const float* __restrict__ gpart,
        const float* __restrict__ Wpart, const float* __restrict__ Bpart,
        const float* __restrict__ b1, const float* __restrict__ w2,
        const float* __restrict__ b2, const float* __restrict__ gum,
        const float* __restrict__ dzv, float* __restrict__ out) {
    const int t = threadIdx.x;
    const int lane = t & 63, w = t >> 6;
    const int token = blockIdx.x * 4 + w;
    const float dz = dzv[token];
    if (fabsf(dz) >= TAU_) return;    // wave-uniform

    const float* xr = x + (size_t)token * C_;
    float pa[4] = {0.f, 0.f, 0.f, 0.f};
#pragma unroll 1
    for (int k = 0; k < HC_; k += 16) {
        const float4 xk0 = ld4(xr + k), xk1 = ld4(xr + k + 4);
        const float4 xk2 = ld4(xr + k + 8), xk3 = ld4(xr + k + 12);
        const float4 wk0 = ld4(lnw + k), wk1 = ld4(lnw + k + 4);
        const float4 wk2 = ld4(lnw + k + 8), wk3 = ld4(lnw + k + 12);
        float w1v[16];
#pragma unroll
        for (int j = 0; j < 16; ++j)
            w1v[j] = w1[(size_t)(k + j) * D_ + lane];
        const float xs[16] = {xk0.x * wk0.x, xk0.y * wk0.y,
                              xk0.z * wk0.z, xk0.w * wk0.w,
                              xk1.x * wk1.x, xk1.y * wk1.y,
                              xk1.z * wk1.z, xk1.w * wk1.w,
                              xk2.x * wk2.x, xk2.y * wk2.y,
                              xk2.z * wk2.z, xk2.w * wk2.w,
                              xk3.x * wk3.x, xk3.y * wk3.y,
                              xk3.z * wk3.z, xk3.w * wk3.w};
#pragma unroll
        for (int j = 0; j < 16; ++j)
            pa[j & 3] = fmaf(xs[j], w1v[j], pa[j & 3]);
    }
    const float p = (pa[0] + pa[1]) + (pa[2] + pa[3]);

    const int b = token >> 10;
    float W1 = 0.f, Bsv = 0.f, gt = 0.f;
#pragma unroll
    for (int q = 0; q < 8; ++q) {
        W1 += Wpart[q * 64 + lane];
        Bsv += Bpart[q * 64 + lane];
        gt += gpart[(size_t)(b * 8 + q) * 64 + lane];
    }
    gt *= (1.f / N_);
    const float2 gv = *reinterpret_cast<const float2*>(gum + token * 2);
    const float mu = muv[token], rs = rsv[token];
    float h = rs * (p - mu * W1) + Bsv + gt + b1[lane];
    h = 0.5f * h * (1.f + erff(h * 0.70710678118654752f));
    const float2 w2v = *reinterpret_cast<const float2*>(w2 + lane * 2);
    float l0 = h * w2v.x;
    float l1 = h * w2v.y;
#pragma unroll
    for (int o = 1; o < 64; o <<= 1) {
        l0 += __shfl_xor(l0, o);
        l1 += __shfl_xor(l1, o);
    }
    const float z0 = l0 + b2[0] + gv.x;
    const float z1 = l1 + b2[1] + gv.y;
    const bool keepNew = (z0 >= z1);
    const bool keepOld = (dz >= 0.f);
    if (keepNew == keepOld) return;

    float4* dst = reinterpret_cast<float4*>(out + (size_t)token * C_);
    if (keepNew) {
        const float4* src = reinterpret_cast<const float4*>(xr);
#pragma unroll
        for (int c = 0; c < 16; ++c)
            dst[c * 64 + lane] = src[c * 64 + lane];
    } else {
        const float4 z = make_float4(0.f, 0.f, 0.f, 0.f);
#pragma unroll
        for (int c = 0; c < 16; ++c)
            dst[c * 64 + lane] = z;
    }
}

// ---------------------------------------------------------------------------
extern "C" void kernel_launch(void* const* d_in, const int* in_sizes, int n_in,
                              void* d_out, int out_size, void* d_ws,
                              size_t ws_size, hipStream_t stream) {
    const float* x   = (const float*)d_in[0];
    const float* gum = (const float*)d_in[1];
    const float* lnw = (const float*)d_in[2];
    const float* lnb = (const float*)d_in[3];
    const float* w1  = (const float*)d_in[4];
    const float* b1  = (const float*)d_in[5];
    const float* w2  = (const float*)d_in[6];
    const float* b2  = (const float*)d_in[7];
    float* out = (float*)d_out;

    float* wsf   = (float*)d_ws;
    float* Pp    = wsf;                                   // 32768*64
    float* muv   = Pp + (size_t)NT_ * D_;                 // 32768
    float* rsv   = muv + NT_;                             // 32768
    float* part  = rsv + NT_;                             // 512*2048
    float* gpart = part + (size_t)512 * HC_;              // 256*64
    float* Wpart = gpart + 256 * 64;                      // 8*64
    float* Bpart = Wpart + 8 * 64;                        // 8*64
    float* dzv   = Bpart + 8 * 64;                        // 32768
    short* whG   = (short*)(dzv + NT_);                   // 131072 shorts

    k0_prep<<<256, 64, 0, stream>>>(lnw, w1, whG);
    mk1m<<<512, 256, 0, stream>>>(x, lnw, lnb, whG, Pp, muv, rsv, part);
    k2a_part<<<264, 256, 0, stream>>>(part, w1, lnw, lnb,
                                      gpart, Wpart, Bpart);
    k45_decide_mask<<<NT_ / 4, 256, 0, stream>>>(Pp, muv, rsv, gpart,
                                                 Wpart, Bpart, b1, w2, b2,
                                                 gum, x, out, dzv);
    k6_cleanup<<<NT_ / 4, 256, 0, stream>>>(x, lnw, w1, muv, rsv, gpart,
                                            Wpart, Bpart, b1, w2, b2,
                                            gum, dzv, out);
}

// Round 20
// 361.040 us; speedup vs baseline: 1.4896x; 1.2346x over previous
//
#include <hip/hip_runtime.h>
#include <math.h>

#define B_   32
#define N_   1024
#define C_   4096
#define HC_  2048
#define D_   64
#define NT_  32768           // B*N tokens
#define BKC_ 128             // K-chunk per staging step (deep streaming)
#define NCH_ (HC_ / BKC_)    // 16 chunks
#define AST_ 68              // As row stride (64 rows + 4 pad)

__device__ __forceinline__ float4 ld4(const float* p) {
    return *reinterpret_cast<const float4*>(p);
}

// ---------------------------------------------------------------------------
// MK1 v6: fused vector GEMM (full K, exact f32) + LN stats + upper g-accum.
// r12 structure with DEEP staging loads: BKC=128, each staging thread loads
// 8 consecutive float4s (128 B in flight -> fixes the measured 0.83 TB/s
// latency-bound G-phase; k1_upper's identical pattern measures ~6 TB/s).
// grid 512 (M64 tiles), block 256.
// Phase G: P[t,d] = sum_k x[t,k]*(lnw[k]*w1[k,d]); thread tile 4r x 4d
//   (acc[16]); As k-major [128][68] + Bs [128][64] in LDS; 2 barriers/chunk.
// Phase U: r12-verbatim upper stats + normalized-upper accumulation.
// LDS: 67.6 KB union (G) / sh[4][2048] (U) -> 2 blocks/CU.
// ---------------------------------------------------------------------------
__global__ __launch_bounds__(256) void mk1(
        const float* __restrict__ x, const float* __restrict__ lnw,
        const float* __restrict__ lnb, const float* __restrict__ w1,
        float* __restrict__ Pp, float* __restrict__ muv,
        float* __restrict__ rsv, float* __restrict__ part) {
    __shared__ float smem[16896];      // 67.6 KB: As[128*68] + Bs[128*64]
    __shared__ float sLow[64], qLow[64];
    float* As = smem;                  // 8704 floats
    float* Bsm = smem + 8704;          // 8192 floats

    const int t = threadIdx.x;
    const int tid = blockIdx.x;
    const int T0 = tid * 64;
    const int rt = t & 15;             // row-quad: rows rt*4 .. rt*4+3
    const int dt = t >> 4;             // col-quad: cols dt*4 .. dt*4+3
    const int row = t >> 2;            // staging row (0..63)
    const int fq = t & 3;              // staging k-block (32 cols each)
    const int lane = t & 63, w = t >> 6;

    // ===================== Phase G: GEMM + lower stats =====================
    float acc[16];
#pragma unroll
    for (int i = 0; i < 16; ++i) acc[i] = 0.f;
    float sR = 0.f, qR = 0.f;

    float4 xv[8];                      // x[T0+row][k0+fq*32 .. +31]
    float4 wv[8];                      // w1 tile (idx i*256+t)
    float lw[8];
    {   // prologue: chunk 0 (8+8 independent b128 loads in flight)
        const float* rp = x + (size_t)(T0 + row) * C_ + fq * 32;
#pragma unroll
        for (int i = 0; i < 8; ++i) xv[i] = ld4(rp + i * 4);
        const float4* s4 = reinterpret_cast<const float4*>(w1);
#pragma unroll
        for (int i = 0; i < 8; ++i) {
            wv[i] = s4[i * 256 + t];
            lw[i] = lnw[(i * 256 + t) >> 4];
        }
    }

#pragma unroll 1
    for (int c = 0; c < NCH_; ++c) {
        // ---- stage A (k-major, stride 68) + stats from regs ----
#pragma unroll
        for (int i = 0; i < 8; ++i) {
            const float4 v = xv[i];
            const int kl = fq * 32 + i * 4;
            As[(kl + 0) * AST_ + row] = v.x;
            As[(kl + 1) * AST_ + row] = v.y;
            As[(kl + 2) * AST_ + row] = v.z;
            As[(kl + 3) * AST_ + row] = v.w;
            sR += (v.x + v.y) + (v.z + v.w);
            qR = fmaf(v.x, v.x, fmaf(v.y, v.y,
                 fmaf(v.z, v.z, fmaf(v.w, v.w, qR))));
        }
        // ---- stage B (lnw-folded) ----
        {
            float4* b4 = reinterpret_cast<float4*>(Bsm);
#pragma unroll
            for (int i = 0; i < 8; ++i) {
                float4 v = wv[i];
                v.x *= lw[i]; v.y *= lw[i]; v.z *= lw[i]; v.w *= lw[i];
                b4[i * 256 + t] = v;
            }
        }
        __syncthreads();
        // ---- prefetch chunk c+1 (16 independent b128s, overlap FMA) ----
        if (c + 1 < NCH_) {
            const int k1 = (c + 1) * BKC_;
            const float* rp = x + (size_t)(T0 + row) * C_ + k1 + fq * 32;
#pragma unroll
            for (int i = 0; i < 8; ++i) xv[i] = ld4(rp + i * 4);
            const float4* s4 = reinterpret_cast<const float4*>(
                w1 + (size_t)k1 * D_);
#pragma unroll
            for (int i = 0; i < 8; ++i) {
                wv[i] = s4[i * 256 + t];
                lw[i] = lnw[k1 + ((i * 256 + t) >> 4)];
            }
        }
        // ---- FMA loop: per k = 2 b128 LDS (2-way, free) + 16 FMA ----
#pragma unroll 8
        for (int k = 0; k < BKC_; ++k) {
            const float4 a4 = *reinterpret_cast<const float4*>(
                As + k * AST_ + rt * 4);
            const float4 b4 = *reinterpret_cast<const float4*>(
                Bsm + k * 64 + dt * 4);
            const float av[4] = {a4.x, a4.y, a4.z, a4.w};
            const float bv[4] = {b4.x, b4.y, b4.z, b4.w};
#pragma unroll
            for (int ri = 0; ri < 4; ++ri)
#pragma unroll
                for (int cj = 0; cj < 4; ++cj)
                    acc[ri * 4 + cj] =
                        fmaf(av[ri], bv[cj], acc[ri * 4 + cj]);
        }
        __syncthreads();
    }
    // ---- write P: rows rt*4+ri, cols dt*4..+3 ----
#pragma unroll
    for (int ri = 0; ri < 4; ++ri) {
        float* dst = Pp + (size_t)(T0 + rt * 4 + ri) * D_ + dt * 4;
        *reinterpret_cast<float4*>(dst) = make_float4(
            acc[ri * 4 + 0], acc[ri * 4 + 1],
            acc[ri * 4 + 2], acc[ri * 4 + 3]);
    }
    // ---- lower-stats reduce: 4 staging threads per row ----
    sR += __shfl_xor(sR, 1); qR += __shfl_xor(qR, 1);
    sR += __shfl_xor(sR, 2); qR += __shfl_xor(qR, 2);
    if (fq == 0) { sLow[row] = sR; qLow[row] = qR; }
    __syncthreads();

    // ===================== Phase U: upper stats + g-accum ==================
    float4 wvu[8], bvu[8], gacc[8];
#pragma unroll
    for (int m = 0; m < 8; ++m) {
        wvu[m] = ld4(lnw + HC_ + (m * 64 + lane) * 4);
        bvu[m] = ld4(lnb + HC_ + (m * 64 + lane) * 4);
        gacc[m] = make_float4(0.f, 0.f, 0.f, 0.f);
    }
    for (int i = 0; i < 16; ++i) {
        const int r = w * 16 + i;
        const int tok = T0 + r;
        const float* rowp = x + (size_t)tok * C_ + HC_;
        float4 v[8];
        float s = 0.f, q = 0.f;
#pragma unroll
        for (int m = 0; m < 8; ++m) {
            v[m] = ld4(rowp + (m * 64 + lane) * 4);
            s += (v[m].x + v[m].y) + (v[m].z + v[m].w);
            q = fmaf(v[m].x, v[m].x, fmaf(v[m].y, v[m].y,
                fmaf(v[m].z, v[m].z, fmaf(v[m].w, v[m].w, q))));
        }
#pragma unroll
        for (int o = 1; o < 64; o <<= 1) {
            s += __shfl_xor(s, o);
            q += __shfl_xor(q, o);
        }
        const float S_ = s + sLow[r];
        const float Q_ = q + qLow[r];
        const float mu = S_ * (1.f / C_);
        const float rs = rsqrtf(Q_ * (1.f / C_) - mu * mu + 1e-5f);
        if (lane == 0) {
            muv[tok] = mu;
            rsv[tok] = rs;
        }
#pragma unroll
        for (int m = 0; m < 8; ++m) {
            gacc[m].x += (v[m].x - mu) * rs * wvu[m].x + bvu[m].x;
            gacc[m].y += (v[m].y - mu) * rs * wvu[m].y + bvu[m].y;
            gacc[m].z += (v[m].z - mu) * rs * wvu[m].z + bvu[m].z;
            gacc[m].w += (v[m].w - mu) * rs * wvu[m].w + bvu[m].w;
        }
    }
    // cross-wave reduction via smem (sh[4][2048]); GEMM buffers dead
    float (*sh)[HC_] = reinterpret_cast<float(*)[HC_]>(smem);
    __syncthreads();
#pragma unroll
    for (int m = 0; m < 8; ++m)
        *reinterpret_cast<float4*>(&sh[w][(m * 64 + lane) * 4]) = gacc[m];
    __syncthreads();
    float* pp = part + (size_t)tid * HC_;
#pragma unroll
    for (int m = 0; m < 8; ++m) {
        const int j = (m * 64 + lane) * 4;
        const float4 a0 = ld4(&sh[0][j]);
        const float4 a1 = ld4(&sh[1][j]);
        const float4 a2 = ld4(&sh[2][j]);
        const float4 a3 = ld4(&sh[3][j]);
        float4 r;
        r.x = (a0.x + a1.x) + (a2.x + a3.x);
        r.y = (a0.y + a1.y) + (a2.y + a3.y);
        r.z = (a0.z + a1.z) + (a2.z + a3.z);
        r.w = (a0.w + a1.w) + (a2.w + a3.w);
        if (w == (m & 3))    // spread the 8 stores across the 4 waves
            *reinterpret_cast<float4*>(pp + j) = r;
    }
}

// ---------------------------------------------------------------------------
// K2a: fold partial-reduce + partial GEMVs.  grid 264, block 256.
// blocks 0..255: (b, jq) — sum 16 partials (512 part rows), then GEMV.
// blocks 256..263: Wpart/Bpart over 256 c each.
// ---------------------------------------------------------------------------
__global__ __launch_bounds__(256) void k2a_part(
        const float* __restrict__ part, const float* __restrict__ w1,
        const float* __restrict__ lnw, const float* __restrict__ lnb,
        float* __restrict__ gpart, float* __restrict__ Wpart,
        float* __restrict__ Bpart) {
    __shared__ float Gs[256];
    __shared__ float red[512];
    const int t = threadIdx.x;
    const int d = t & 63, s = t >> 6;
    const int blk = blockIdx.x;
    if (blk < 256) {
        const int b = blk >> 3, jq = blk & 7;
        const int j = jq * 256 + t;
        float a = 0.f;
        for (int k = 0; k < 16; ++k)
            a += part[(size_t)(b * 16 + k) * HC_ + j];
        Gs[t] = a;
        __syncthreads();
        float acc = 0.f;
        const int j0 = jq * 256 + s * 64;
        for (int jj = 0; jj < 64; ++jj)
            acc = fmaf(Gs[s * 64 + jj],
                       w1[(size_t)(HC_ + j0 + jj) * D_ + d], acc);
        red[s * 64 + d] = acc;
        __syncthreads();
        if (s == 0)
            gpart[(size_t)blk * 64 + d] =
                red[d] + red[64 + d] + red[128 + d] + red[192 + d];
    } else {
        const int wq = blk - 256;
        const int c0 = wq * 256 + s * 64;
        float a = 0.f, c2 = 0.f;
        for (int c = c0; c < c0 + 64; ++c) {
            const float wvv = w1[(size_t)c * D_ + d];
            a = fmaf(lnw[c], wvv, a);
            c2 = fmaf(lnb[c], wvv, c2);
        }
        red[s * 64 + d] = a;
        red[256 + s * 64 + d] = c2;
        __syncthreads();
        if (s == 0) {
            Wpart[wq * 64 + d] =
                red[d] + red[64 + d] + red[128 + d] + red[192 + d];
            Bpart[wq * 64 + d] = red[256 + d] + red[320 + d]
                               + red[384 + d] + red[448 + d];
        }
    }
}

// ---------------------------------------------------------------------------
// K45: decision (k2b folded) + masked copy.  One wave per token.
// Dropped tokens write zeros WITHOUT reading x.  grid 8192, block 256.
// ---------------------------------------------------------------------------
__global__ __launch_bounds__(256) void k45_decide_mask(
        const float* __restrict__ Pp, const float* __restrict__ muv,
        const float* __restrict__ rsv, const float* __restrict__ gpart,
        const float* __restrict__ Wpart, const float* __restrict__ Bpart,
        const float* __restrict__ b1, const float* __restrict__ w2,
        const float* __restrict__ b2, const float* __restrict__ gum,
        const float* __restrict__ x, float* __restrict__ out) {
    const int t = threadIdx.x;
    const int lane = t & 63, w = t >> 6;
    const int token = blockIdx.x * 4 + w;
    const int b = token >> 10;

    // ---- folded k2b: W1s/Bs/gterm for this lane (L2-hot) ----
    float W1 = 0.f, Bsv = 0.f, gt = 0.f;
#pragma unroll
    for (int q = 0; q < 8; ++q) {
        W1 += Wpart[q * 64 + lane];
        Bsv += Bpart[q * 64 + lane];
        gt += gpart[(size_t)(b * 8 + q) * 64 + lane];
    }
    gt *= (1.f / N_);

    const float2 gv = *reinterpret_cast<const float2*>(gum + token * 2);
    const float p = Pp[(size_t)token * D_ + lane];
    const float mu = muv[token], rs = rsv[token];
    float h = rs * (p - mu * W1) + Bsv + gt + b1[lane];
    h = 0.5f * h * (1.f + erff(h * 0.70710678118654752f));   // exact gelu
    const float2 w2v = *reinterpret_cast<const float2*>(w2 + lane * 2);
    float l0 = h * w2v.x;
    float l1 = h * w2v.y;
#pragma unroll
    for (int o = 1; o < 64; o <<= 1) {
        l0 += __shfl_xor(l0, o);
        l1 += __shfl_xor(l1, o);
    }
    const float z0 = l0 + b2[0] + gv.x;
    const float z1 = l1 + b2[1] + gv.y;

    float4* dst = reinterpret_cast<float4*>(out + (size_t)token * C_);
    if (z0 >= z1) {    // keep (argmax ties -> index 0): copy x
        const float4* src =
            reinterpret_cast<const float4*>(x + (size_t)token * C_);
#pragma unroll
        for (int c = 0; c < 16; ++c)
            dst[c * 64 + lane] = src[c * 64 + lane];
    } else {           // drop: write zeros, skip the x read
        const float4 z = make_float4(0.f, 0.f, 0.f, 0.f);
#pragma unroll
        for (int c = 0; c < 16; ++c)
            dst[c * 64 + lane] = z;
    }
}

// ---------------------------------------------------------------------------
extern "C" void kernel_launch(void* const* d_in, const int* in_sizes, int n_in,
                              void* d_out, int out_size, void* d_ws,
                              size_t ws_size, hipStream_t stream) {
    const float* x   = (const float*)d_in[0];
    const float* gum = (const float*)d_in[1];
    const float* lnw = (const float*)d_in[2];
    const float* lnb = (const float*)d_in[3];
    const float* w1  = (const float*)d_in[4];
    const float* b1  = (const float*)d_in[5];
    const float* w2  = (const float*)d_in[6];
    const float* b2  = (const float*)d_in[7];
    float* out = (float*)d_out;

    float* wsf   = (float*)d_ws;
    float* Pp    = wsf;                                   // 32768*64
    float* muv   = Pp + (size_t)NT_ * D_;                 // 32768
    float* rsv   = muv + NT_;                             // 32768
    float* part  = rsv + NT_;                             // 512*2048
    float* gpart = part + (size_t)512 * HC_;              // 256*64
    float* Wpart = gpart + 256 * 64;                      // 8*64
    float* Bpart = Wpart + 8 * 64;                        // 8*64

    mk1<<<512, 256, 0, stream>>>(x, lnw, lnb, w1, Pp, muv, rsv, part);
    k2a_part<<<264, 256, 0, stream>>>(part, w1, lnw, lnb,
                                      gpart, Wpart, Bpart);
    k45_decide_mask<<<NT_ / 4, 256, 0, stream>>>(Pp, muv, rsv, gpart,
                                                 Wpart, Bpart, b1, w2, b2,
                                                 gum, x, out);
}

// Round 21
// 351.361 us; speedup vs baseline: 1.5306x; 1.0275x over previous
//
#include <hip/hip_runtime.h>
#include <math.h>

#define B_   32
#define N_   1024
#define C_   4096
#define HC_  2048
#define D_   64
#define NT_  32768           // B*N tokens
#define BKC_ 128             // K-chunk per staging step (deep streaming)
#define NCH_ (HC_ / BKC_)    // 16 chunks
#define AST_ 68              // As row stride (64 rows + 4 pad)

__device__ __forceinline__ float4 ld4(const float* p) {
    return *reinterpret_cast<const float4*>(p);
}

// ---------------------------------------------------------------------------
// MK1 v7: fused vector GEMM (exact f32) + LN stats + upper g-accum.
// grid 512 (M64 tiles), block 256.
// G phase: 8r x 8d thread tile (acc[64]) + K-SPLIT ACROSS WAVES (wave w
// handles k in [w*32,(w+1)*32) of each 128-chunk) -> 4 LDS b128 per 64 FMA
// and each k read by ONE wave: LDS-read pipe time drops ~164 -> ~50 us.
// Wave-partial accs reduced once through LDS at the end.
// Staging: deep (8 consecutive b128 per thread), r20-verbatim.
// Phase U: r20-verbatim.  LDS 67.6 KB union -> 2 blocks/CU.
// ---------------------------------------------------------------------------
__global__ __launch_bounds__(256) void mk1(
        const float* __restrict__ x, const float* __restrict__ lnw,
        const float* __restrict__ lnb, const float* __restrict__ w1,
        float* __restrict__ Pp, float* __restrict__ muv,
        float* __restrict__ rsv, float* __restrict__ part) {
    __shared__ float smem[16896];      // 67.6 KB union
    __shared__ float sLow[64], qLow[64];
    float* As = smem;                  // [128][68] k-major
    float* Bsm = smem + 8704;          // [128][64]

    const int t = threadIdx.x;
    const int tid = blockIdx.x;
    const int T0 = tid * 64;
    const int row = t >> 2;            // staging row (0..63)
    const int fq = t & 3;              // staging k-block (32 cols each)
    const int lane = t & 63, w = t >> 6;
    const int rt = lane >> 3, dt = lane & 7;   // 8x8 FMA tile coords

    // ===================== Phase G: GEMM + lower stats =====================
    float acc[64];
#pragma unroll
    for (int i = 0; i < 64; ++i) acc[i] = 0.f;
    float sR = 0.f, qR = 0.f;

    float4 xv[8];                      // x[T0+row][k0+fq*32 .. +31]
    float4 wv[8];                      // w1 tile (idx i*256+t)
    float lw[8];
    {   // prologue: chunk 0 (8+8 independent b128 loads in flight)
        const float* rp = x + (size_t)(T0 + row) * C_ + fq * 32;
#pragma unroll
        for (int i = 0; i < 8; ++i) xv[i] = ld4(rp + i * 4);
        const float4* s4 = reinterpret_cast<const float4*>(w1);
#pragma unroll
        for (int i = 0; i < 8; ++i) {
            wv[i] = s4[i * 256 + t];
            lw[i] = lnw[(i * 256 + t) >> 4];
        }
    }

#pragma unroll 1
    for (int c = 0; c < NCH_; ++c) {
        // ---- stage A (k-major, stride 68) + stats from regs ----
#pragma unroll
        for (int i = 0; i < 8; ++i) {
            const float4 v = xv[i];
            const int kl = fq * 32 + i * 4;
            As[(kl + 0) * AST_ + row] = v.x;
            As[(kl + 1) * AST_ + row] = v.y;
            As[(kl + 2) * AST_ + row] = v.z;
            As[(kl + 3) * AST_ + row] = v.w;
            sR += (v.x + v.y) + (v.z + v.w);
            qR = fmaf(v.x, v.x, fmaf(v.y, v.y,
                 fmaf(v.z, v.z, fmaf(v.w, v.w, qR))));
        }
        // ---- stage B (lnw-folded) ----
        {
            float4* b4 = reinterpret_cast<float4*>(Bsm);
#pragma unroll
            for (int i = 0; i < 8; ++i) {
                float4 v = wv[i];
                v.x *= lw[i]; v.y *= lw[i]; v.z *= lw[i]; v.w *= lw[i];
                b4[i * 256 + t] = v;
            }
        }
        __syncthreads();
        // ---- prefetch chunk c+1 (16 independent b128s, overlap FMA) ----
        if (c + 1 < NCH_) {
            const int k1 = (c + 1) * BKC_;
            const float* rp = x + (size_t)(T0 + row) * C_ + k1 + fq * 32;
#pragma unroll
            for (int i = 0; i < 8; ++i) xv[i] = ld4(rp + i * 4);
            const float4* s4 = reinterpret_cast<const float4*>(
                w1 + (size_t)k1 * D_);
#pragma unroll
            for (int i = 0; i < 8; ++i) {
                wv[i] = s4[i * 256 + t];
                lw[i] = lnw[k1 + ((i * 256 + t) >> 4)];
            }
        }
        // ---- FMA: wave w handles its 32-k quarter; 4 b128 per 64 FMA ----
#pragma unroll 8
        for (int kk = 0; kk < 32; ++kk) {
            const int k = w * 32 + kk;
            const float4 a0 = *reinterpret_cast<const float4*>(
                As + k * AST_ + rt * 8);
            const float4 a1 = *reinterpret_cast<const float4*>(
                As + k * AST_ + rt * 8 + 4);
            const float4 b0 = *reinterpret_cast<const float4*>(
                Bsm + k * 64 + dt * 8);
            const float4 b1 = *reinterpret_cast<const float4*>(
                Bsm + k * 64 + dt * 8 + 4);
            const float av[8] = {a0.x, a0.y, a0.z, a0.w,
                                 a1.x, a1.y, a1.z, a1.w};
            const float bv[8] = {b0.x, b0.y, b0.z, b0.w,
                                 b1.x, b1.y, b1.z, b1.w};
#pragma unroll
            for (int ri = 0; ri < 8; ++ri)
#pragma unroll
                for (int cj = 0; cj < 8; ++cj)
                    acc[ri * 8 + cj] =
                        fmaf(av[ri], bv[cj], acc[ri * 8 + cj]);
        }
        __syncthreads();
    }
    // ---- lower-stats reduce: 4 staging threads per row ----
    sR += __shfl_xor(sR, 1); qR += __shfl_xor(qR, 1);
    sR += __shfl_xor(sR, 2); qR += __shfl_xor(qR, 2);
    if (fq == 0) { sLow[row] = sR; qLow[row] = qR; }

    // ---- cross-wave acc reduce via smem (As/Bsm dead) + P write ----
#pragma unroll
    for (int i = 0; i < 64; ++i) smem[i * 256 + t] = acc[i];
    __syncthreads();
#pragma unroll
    for (int r2 = 0; r2 < 2; ++r2) {
        const int rowO = rt * 8 + w * 2 + r2;
        float v[8];
#pragma unroll
        for (int cj = 0; cj < 8; ++cj) {
            const int i = w * 16 + r2 * 8 + cj;
            v[cj] = (smem[i * 256 + lane]
                     + smem[i * 256 + 64 + lane])
                  + (smem[i * 256 + 128 + lane]
                     + smem[i * 256 + 192 + lane]);
        }
        float* dst = Pp + (size_t)(T0 + rowO) * D_ + dt * 8;
        *reinterpret_cast<float4*>(dst) =
            make_float4(v[0], v[1], v[2], v[3]);
        *reinterpret_cast<float4*>(dst + 4) =
            make_float4(v[4], v[5], v[6], v[7]);
    }
    __syncthreads();

    // ===================== Phase U: upper stats + g-accum ==================
    float4 wvu[8], bvu[8], gacc[8];
#pragma unroll
    for (int m = 0; m < 8; ++m) {
        wvu[m] = ld4(lnw + HC_ + (m * 64 + lane) * 4);
        bvu[m] = ld4(lnb + HC_ + (m * 64 + lane) * 4);
        gacc[m] = make_float4(0.f, 0.f, 0.f, 0.f);
    }
    for (int i = 0; i < 16; ++i) {
        const int r = w * 16 + i;
        const int tok = T0 + r;
        const float* rowp = x + (size_t)tok * C_ + HC_;
        float4 v[8];
        float s = 0.f, q = 0.f;
#pragma unroll
        for (int m = 0; m < 8; ++m) {
            v[m] = ld4(rowp + (m * 64 + lane) * 4);
            s += (v[m].x + v[m].y) + (v[m].z + v[m].w);
            q = fmaf(v[m].x, v[m].x, fmaf(v[m].y, v[m].y,
                fmaf(v[m].z, v[m].z, fmaf(v[m].w, v[m].w, q))));
        }
#pragma unroll
        for (int o = 1; o < 64; o <<= 1) {
            s += __shfl_xor(s, o);
            q += __shfl_xor(q, o);
        }
        const float S_ = s + sLow[r];
        const float Q_ = q + qLow[r];
        const float mu = S_ * (1.f / C_);
        const float rs = rsqrtf(Q_ * (1.f / C_) - mu * mu + 1e-5f);
        if (lane == 0) {
            muv[tok] = mu;
            rsv[tok] = rs;
        }
#pragma unroll
        for (int m = 0; m < 8; ++m) {
            gacc[m].x += (v[m].x - mu) * rs * wvu[m].x + bvu[m].x;
            gacc[m].y += (v[m].y - mu) * rs * wvu[m].y + bvu[m].y;
            gacc[m].z += (v[m].z - mu) * rs * wvu[m].z + bvu[m].z;
            gacc[m].w += (v[m].w - mu) * rs * wvu[m].w + bvu[m].w;
        }
    }
    // cross-wave reduction via smem (sh[4][2048])
    float (*sh)[HC_] = reinterpret_cast<float(*)[HC_]>(smem);
    __syncthreads();
#pragma unroll
    for (int m = 0; m < 8; ++m)
        *reinterpret_cast<float4*>(&sh[w][(m * 64 + lane) * 4]) = gacc[m];
    __syncthreads();
    float* pp = part + (size_t)tid * HC_;
#pragma unroll
    for (int m = 0; m < 8; ++m) {
        const int j = (m * 64 + lane) * 4;
        const float4 a0 = ld4(&sh[0][j]);
        const float4 a1 = ld4(&sh[1][j]);
        const float4 a2 = ld4(&sh[2][j]);
        const float4 a3 = ld4(&sh[3][j]);
        float4 r;
        r.x = (a0.x + a1.x) + (a2.x + a3.x);
        r.y = (a0.y + a1.y) + (a2.y + a3.y);
        r.z = (a0.z + a1.z) + (a2.z + a3.z);
        r.w = (a0.w + a1.w) + (a2.w + a3.w);
        if (w == (m & 3))    // spread the 8 stores across the 4 waves
            *reinterpret_cast<float4*>(pp + j) = r;
    }
}

// ---------------------------------------------------------------------------
// K2a: fold partial-reduce + partial GEMVs.  grid 264, block 256.
// ---------------------------------------------------------------------------
__global__ __launch_bounds__(256) void k2a_part(
        const float* __restrict__ part, const float* __restrict__ w1,
        const float* __restrict__ lnw, const float* __restrict__ lnb,
        float* __restrict__ gpart, float* __restrict__ Wpart,
        float* __restrict__ Bpart) {
    __shared__ float Gs[256];
    __shared__ float red[512];
    const int t = threadIdx.x;
    const int d = t & 63, s = t >> 6;
    const int blk = blockIdx.x;
    if (blk < 256) {
        const int b = blk >> 3, jq = blk & 7;
        const int j = jq * 256 + t;
        float a = 0.f;
        for (int k = 0; k < 16; ++k)
            a += part[(size_t)(b * 16 + k) * HC_ + j];
        Gs[t] = a;
        __syncthreads();
        float acc = 0.f;
        const int j0 = jq * 256 + s * 64;
        for (int jj = 0; jj < 64; ++jj)
            acc = fmaf(Gs[s * 64 + jj],
                       w1[(size_t)(HC_ + j0 + jj) * D_ + d], acc);
        red[s * 64 + d] = acc;
        __syncthreads();
        if (s == 0)
            gpart[(size_t)blk * 64 + d] =
                red[d] + red[64 + d] + red[128 + d] + red[192 + d];
    } else {
        const int wq = blk - 256;
        const int c0 = wq * 256 + s * 64;
        float a = 0.f, c2 = 0.f;
        for (int c = c0; c < c0 + 64; ++c) {
            const float wvv = w1[(size_t)c * D_ + d];
            a = fmaf(lnw[c], wvv, a);
            c2 = fmaf(lnb[c], wvv, c2);
        }
        red[s * 64 + d] = a;
        red[256 + s * 64 + d] = c2;
        __syncthreads();
        if (s == 0) {
            Wpart[wq * 64 + d] =
                red[d] + red[64 + d] + red[128 + d] + red[192 + d];
            Bpart[wq * 64 + d] = red[256 + d] + red[320 + d]
                               + red[384 + d] + red[448 + d];
        }
    }
}

// ---------------------------------------------------------------------------
// K45: decision (k2b folded) + masked copy.  One wave per token.
// Dropped tokens write zeros WITHOUT reading x.  grid 8192, block 256.
// ---------------------------------------------------------------------------
__global__ __launch_bounds__(256) void k45_decide_mask(
        const float* __restrict__ Pp, const float* __restrict__ muv,
        const float* __restrict__ rsv, const float* __restrict__ gpart,
        const float* __restrict__ Wpart, const float* __restrict__ Bpart,
        const float* __restrict__ b1, const float* __restrict__ w2,
        const float* __restrict__ b2, const float* __restrict__ gum,
        const float* __restrict__ x, float* __restrict__ out) {
    const int t = threadIdx.x;
    const int lane = t & 63, w = t >> 6;
    const int token = blockIdx.x * 4 + w;
    const int b = token >> 10;

    // ---- folded k2b: W1s/Bs/gterm for this lane (L2-hot) ----
    float W1 = 0.f, Bsv = 0.f, gt = 0.f;
#pragma unroll
    for (int q = 0; q < 8; ++q) {
        W1 += Wpart[q * 64 + lane];
        Bsv += Bpart[q * 64 + lane];
        gt += gpart[(size_t)(b * 8 + q) * 64 + lane];
    }
    gt *= (1.f / N_);

    const float2 gv = *reinterpret_cast<const float2*>(gum + token * 2);
    const float p = Pp[(size_t)token * D_ + lane];
    const float mu = muv[token], rs = rsv[token];
    float h = rs * (p - mu * W1) + Bsv + gt + b1[lane];
    h = 0.5f * h * (1.f + erff(h * 0.70710678118654752f));   // exact gelu
    const float2 w2v = *reinterpret_cast<const float2*>(w2 + lane * 2);
    float l0 = h * w2v.x;
    float l1 = h * w2v.y;
#pragma unroll
    for (int o = 1; o < 64; o <<= 1) {
        l0 += __shfl_xor(l0, o);
        l1 += __shfl_xor(l1, o);
    }
    const float z0 = l0 + b2[0] + gv.x;
    const float z1 = l1 + b2[1] + gv.y;

    float4* dst = reinterpret_cast<float4*>(out + (size_t)token * C_);
    if (z0 >= z1) {    // keep (argmax ties -> index 0): copy x
        const float4* src =
            reinterpret_cast<const float4*>(x + (size_t)token * C_);
#pragma unroll
        for (int c = 0; c < 16; ++c)
            dst[c * 64 + lane] = src[c * 64 + lane];
    } else {           // drop: write zeros, skip the x read
        const float4 z = make_float4(0.f, 0.f, 0.f, 0.f);
#pragma unroll
        for (int c = 0; c < 16; ++c)
            dst[c * 64 + lane] = z;
    }
}

// ---------------------------------------------------------------------------
extern "C" void kernel_launch(void* const* d_in, const int* in_sizes, int n_in,
                              void* d_out, int out_size, void* d_ws,
                              size_t ws_size, hipStream_t stream) {
    const float* x   = (const float*)d_in[0];
    const float* gum = (const float*)d_in[1];
    const float* lnw = (const float*)d_in[2];
    const float* lnb = (const float*)d_in[3];
    const float* w1  = (const float*)d_in[4];
    const float* b1  = (const float*)d_in[5];
    const float* w2  = (const float*)d_in[6];
    const float* b2  = (const float*)d_in[7];
    float* out = (float*)d_out;

    float* wsf   = (float*)d_ws;
    float* Pp    = wsf;                                   // 32768*64
    float* muv   = Pp + (size_t)NT_ * D_;                 // 32768
    float* rsv   = muv + NT_;                             // 32768
    float* part  = rsv + NT_;                             // 512*2048
    float* gpart = part + (size_t)512 * HC_;              // 256*64
    float* Wpart = gpart + 256 * 64;                      // 8*64
    float* Bpart = Wpart + 8 * 64;                        // 8*64

    mk1<<<512, 256, 0, stream>>>(x, lnw, lnb, w1, Pp, muv, rsv, part);
    k2a_part<<<264, 256, 0, stream>>>(part, w1, lnw, lnb,
                                      gpart, Wpart, Bpart);
    k45_decide_mask<<<NT_ / 4, 256, 0, stream>>>(Pp, muv, rsv, gpart,
                                                 Wpart, Bpart, b1, w2, b2,
                                                 gum, x, out);
}